// Round 1
// baseline (310.737 us; speedup 1.0000x reference)
//
#include <hip/hip_runtime.h>
#include <math.h>

#define D_INNER 1024
#define STATE   16
#define DT_RANK 64
#define NPROJ   96   // DT_RANK + 2*STATE
#define LSEQ    1024
#define NBATCH  2

// ---------------- Kernel 1: proj = x @ W_xproj  (rows=2048, K=1024, N=96) ----
__global__ void proj_kernel(const float* __restrict__ x,
                            const float* __restrict__ Wx,
                            float* __restrict__ proj) {
    int row = blockIdx.x;            // 0..2047  (b*L + l)
    int j   = threadIdx.x;           // 0..127 (96 active)
    __shared__ float xs[D_INNER];
    const float* xrow = x + (size_t)row * D_INNER;
    for (int k = threadIdx.x; k < D_INNER; k += blockDim.x)
        xs[k] = xrow[k];
    __syncthreads();
    if (j < NPROJ) {
        float acc = 0.f;
        #pragma unroll 8
        for (int k = 0; k < D_INNER; ++k)
            acc = fmaf(xs[k], Wx[k * NPROJ + j], acc);
        proj[(size_t)row * NPROJ + j] = acc;
    }
}

// ------------- Kernel 2: delta = softplus(proj[:, :64] @ W_dt + b_dt) -------
__global__ void delta_kernel(const float* __restrict__ proj,
                             const float* __restrict__ Wdt,
                             const float* __restrict__ bdt,
                             float* __restrict__ delta) {
    int idx = blockIdx.x * blockDim.x + threadIdx.x;  // row*1024 + d
    int row = idx >> 10;
    int d   = idx & 1023;
    const float* prow = proj + (size_t)row * NPROJ;
    float acc = bdt[d];
    #pragma unroll
    for (int k = 0; k < DT_RANK; ++k)
        acc = fmaf(prow[k], Wdt[k * D_INNER + d], acc);
    // softplus = logaddexp(acc, 0) = max(acc,0) + log1p(exp(-|acc|))
    float sp = fmaxf(acc, 0.f) + log1pf(__expf(-fabsf(acc)));
    delta[idx] = sp;
}

// ------------- Kernel 3: the clamped "scan" (two cumsums) + C-contraction ----
// One thread per (d,n) chain. Block = 64 threads = 4 d-values x 16 states.
// Grid = NBATCH * (D_INNER/4) = 512 blocks.
__global__ void scan_kernel(const float* __restrict__ x,
                            const float* __restrict__ proj,
                            const float* __restrict__ delta,
                            const float* __restrict__ A_log,
                            const float* __restrict__ Dvec,
                            float* __restrict__ y) {
    const int tid  = threadIdx.x;
    const int n    = tid & 15;
    const int dsub = tid >> 4;                 // 0..3
    const int b    = blockIdx.x >> 8;          // 0..1 (256 blocks per batch)
    const int d    = ((blockIdx.x & 255) << 2) + dsub;

    const float A  = -__expf(A_log[d * STATE + n]);   // matches -exp(A_log)
    const float Dd = Dvec[d];

    float cum = 0.f;   // log_R (running)
    float S   = 0.f;   // cumsum of delta_B_u * exp(min(-log_R,20))

    const int CH = 8;
    for (int l0 = 0; l0 < LSEQ; l0 += CH) {
        float dv[CH], xv[CH], Bv[CH], Cv[CH];
        #pragma unroll
        for (int j = 0; j < CH; ++j) {
            const size_t row = (size_t)b * LSEQ + (l0 + j);
            dv[j] = delta[row * D_INNER + d];
            xv[j] = x[row * D_INNER + d];
            Bv[j] = proj[row * NPROJ + DT_RANK + n];
            Cv[j] = proj[row * NPROJ + DT_RANK + STATE + n];
        }
        #pragma unroll
        for (int j = 0; j < CH; ++j) {
            // log_dA = clip(delta*A, -7, 20); (delta*A <= 0 so upper clip inert)
            float p = fminf(fmaxf(dv[j] * A, -7.0f), 20.0f);
            cum += p;
            // exp_neg_log_R term
            float E = __expf(fminf(-cum, 20.0f));
            // S cumsum of delta_B_u * E
            S = fmaf(dv[j] * Bv[j] * xv[j], E, S);
            // h = exp(min(log_R,20)) * S
            float h = __expf(fminf(cum, 20.0f)) * S;
            float v = Cv[j] * h;
            // reduce over n (16-lane butterfly)
            v += __shfl_xor(v, 1, 16);
            v += __shfl_xor(v, 2, 16);
            v += __shfl_xor(v, 4, 16);
            v += __shfl_xor(v, 8, 16);
            if (n == 0) {
                const size_t row = (size_t)b * LSEQ + (l0 + j);
                y[row * D_INNER + d] = fmaf(xv[j], Dd, v);
            }
        }
    }
}

extern "C" void kernel_launch(void* const* d_in, const int* in_sizes, int n_in,
                              void* d_out, int out_size, void* d_ws, size_t ws_size,
                              hipStream_t stream) {
    const float* x    = (const float*)d_in[0];
    const float* Wx   = (const float*)d_in[1];
    const float* Wdt  = (const float*)d_in[2];
    const float* bdt  = (const float*)d_in[3];
    const float* Alog = (const float*)d_in[4];
    const float* Dvec = (const float*)d_in[5];
    float* y = (float*)d_out;

    // workspace layout: proj (2048*96 f32) | delta (2048*1024 f32)  ~8.75 MB
    float* proj  = (float*)d_ws;
    float* delta = proj + (size_t)NBATCH * LSEQ * NPROJ;

    proj_kernel<<<NBATCH * LSEQ, 128, 0, stream>>>(x, Wx, proj);
    delta_kernel<<<(NBATCH * LSEQ * D_INNER) / 256, 256, 0, stream>>>(proj, Wdt, bdt, delta);
    scan_kernel<<<NBATCH * 256, 64, 0, stream>>>(x, proj, delta, Alog, Dvec, y);
}

// Round 2
// 113.522 us; speedup vs baseline: 2.7372x; 2.7372x over previous
//
#include <hip/hip_runtime.h>
#include <math.h>

#define D_INNER 1024
#define STATE   16
#define DT_RANK 64
#define NPROJ   96
#define LSEQ    1024
#define NBATCH  2

// ============ Kernel 1: proj = x @ W_xproj, split outputs ============
// grid 512 blocks x 384 threads. Each block: 4 rows, K split across 4
// wave-groups (kq), reduced in LDS. Outputs:
//   projdt[row][64]        (dt_inter, row-major)
//   Bg[b][n][L], Cg[b][n][L] (transposed for the scan)
__global__ __launch_bounds__(384) void proj_kernel(
        const float* __restrict__ x, const float* __restrict__ Wx,
        float* __restrict__ projdt, float* __restrict__ Bg, float* __restrict__ Cg) {
    const int tid = threadIdx.x;
    const int j  = tid % 96;
    const int kq = tid / 96;              // 0..3
    const int row0 = blockIdx.x * 4;

    const float* wp = Wx + (size_t)(kq * 256) * 96 + j;
    const float* xr0 = x + (size_t)(row0 + 0) * 1024 + kq * 256;
    const float* xr1 = x + (size_t)(row0 + 1) * 1024 + kq * 256;
    const float* xr2 = x + (size_t)(row0 + 2) * 1024 + kq * 256;
    const float* xr3 = x + (size_t)(row0 + 3) * 1024 + kq * 256;

    float a0 = 0.f, a1 = 0.f, a2 = 0.f, a3 = 0.f;
    #pragma unroll 8
    for (int k = 0; k < 256; ++k) {
        float w = wp[(size_t)k * 96];
        a0 = fmaf(xr0[k], w, a0);
        a1 = fmaf(xr1[k], w, a1);
        a2 = fmaf(xr2[k], w, a2);
        a3 = fmaf(xr3[k], w, a3);
    }

    __shared__ float red[4][4][96];       // [kq][r][j]
    red[kq][0][j] = a0; red[kq][1][j] = a1;
    red[kq][2][j] = a2; red[kq][3][j] = a3;
    __syncthreads();
    if (kq == 0) {
        #pragma unroll
        for (int r = 0; r < 4; ++r) {
            float s = red[0][r][j] + red[1][r][j] + red[2][r][j] + red[3][r][j];
            int row = row0 + r;
            int b = row >> 10, l = row & 1023;
            if (j < 64)       projdt[(size_t)row * 64 + j] = s;
            else if (j < 80)  Bg[((size_t)b * 16 + (j - 64)) * 1024 + l] = s;
            else              Cg[((size_t)b * 16 + (j - 80)) * 1024 + l] = s;
        }
    }
}

// ============ Kernel 2: delta = softplus(projdt @ W_dt + b_dt), transposed out ==========
// grid 512 = 32 l-tiles x 16 d-tiles; block 256. LDS-staged, writes delta_t[b][d][L].
__global__ __launch_bounds__(256) void delta_kernel(
        const float* __restrict__ projdt, const float* __restrict__ Wdt,
        const float* __restrict__ bdt, float* __restrict__ delta_t) {
    const int bid = blockIdx.x;
    const int lt = bid >> 4;              // 0..31
    const int dt = bid & 15;              // 0..15
    const int row0 = lt * 64;
    const int d0 = dt * 64;
    const int tid = threadIdx.x;

    __shared__ float pl[64][69];          // proj tile [l][k]
    __shared__ float wl[64][68];          // Wdt tile  [k][d]
    __shared__ float dtile[64][65];       // delta tile [d][l]

    {   // stage projdt: 64 rows x 64 k, contiguous 16KB
        const float4* src = (const float4*)(projdt + (size_t)row0 * 64);
        #pragma unroll
        for (int i = 0; i < 4; ++i) {
            int f4i = tid + 256 * i;      // 0..1023
            float4 v = src[f4i];
            int l = f4i >> 4, k4 = (f4i & 15) << 2;
            pl[l][k4+0] = v.x; pl[l][k4+1] = v.y; pl[l][k4+2] = v.z; pl[l][k4+3] = v.w;
        }
    }
    {   // stage Wdt chunk: 64k x 64d
        #pragma unroll
        for (int i = 0; i < 4; ++i) {
            int f4i = tid + 256 * i;
            int k = f4i >> 4, m4 = (f4i & 15) << 2;
            float4 v = *(const float4*)(Wdt + (size_t)k * 1024 + d0 + m4);
            *(float4*)&wl[k][m4] = v;
        }
    }
    __syncthreads();

    const int lsub = tid & 63;
    const int dq = tid >> 6;              // wave id, 16 d's per wave
    float acc[16];
    #pragma unroll
    for (int i = 0; i < 16; ++i) acc[i] = 0.f;

    #pragma unroll 4
    for (int k = 0; k < 64; ++k) {
        float p = pl[lsub][k];
        const float4* wr = (const float4*)&wl[k][dq * 16];
        float4 w0 = wr[0], w1 = wr[1], w2 = wr[2], w3 = wr[3];
        acc[0]  = fmaf(p, w0.x, acc[0]);  acc[1]  = fmaf(p, w0.y, acc[1]);
        acc[2]  = fmaf(p, w0.z, acc[2]);  acc[3]  = fmaf(p, w0.w, acc[3]);
        acc[4]  = fmaf(p, w1.x, acc[4]);  acc[5]  = fmaf(p, w1.y, acc[5]);
        acc[6]  = fmaf(p, w1.z, acc[6]);  acc[7]  = fmaf(p, w1.w, acc[7]);
        acc[8]  = fmaf(p, w2.x, acc[8]);  acc[9]  = fmaf(p, w2.y, acc[9]);
        acc[10] = fmaf(p, w2.z, acc[10]); acc[11] = fmaf(p, w2.w, acc[11]);
        acc[12] = fmaf(p, w3.x, acc[12]); acc[13] = fmaf(p, w3.y, acc[13]);
        acc[14] = fmaf(p, w3.z, acc[14]); acc[15] = fmaf(p, w3.w, acc[15]);
    }

    #pragma unroll
    for (int i = 0; i < 16; ++i) {
        float v = acc[i] + bdt[d0 + dq * 16 + i];
        float sp = fmaxf(v, 0.f) + log1pf(__expf(-fabsf(v)));
        dtile[dq * 16 + i][lsub] = sp;
    }
    __syncthreads();

    {   // write out transposed, coalesced
        int dp_ = tid >> 2, seg = tid & 3;
        int b = row0 >> 10, l0 = row0 & 1023;
        float* dst = delta_t + ((size_t)b * 1024 + d0 + dp_) * 1024 + l0 + seg * 16;
        #pragma unroll
        for (int m = 0; m < 4; ++m) {
            float4 v;
            v.x = dtile[dp_][seg*16 + m*4 + 0];
            v.y = dtile[dp_][seg*16 + m*4 + 1];
            v.z = dtile[dp_][seg*16 + m*4 + 2];
            v.w = dtile[dp_][seg*16 + m*4 + 3];
            ((float4*)dst)[m] = v;
        }
    }
}

// ============ Kernel 3: wave-parallel clamped scan ============
// One wave per (b,d); lane i owns l in [16i, 16i+16); all 16 states in regs.
// 3 passes: p-sums -> shfl scan -> q-sums -> shfl scan -> y.
__global__ __launch_bounds__(256) void scan_kernel(
        const float* __restrict__ delta_t, const float* __restrict__ x,
        const float* __restrict__ Bg, const float* __restrict__ Cg,
        const float* __restrict__ A_log, const float* __restrict__ Dvec,
        float* __restrict__ y) {
    const int id = blockIdx.x;                   // 0..511
    const int nid = (id & 7) * 64 + (id >> 3);   // XCD-chunked swizzle (512 = 8*64)
    const int b  = nid >> 8;
    const int dg = nid & 255;
    const int lane = threadIdx.x & 63;
    const int d = dg * 4 + (threadIdx.x >> 6);

    const float Dd = Dvec[d];
    float A[16];
    #pragma unroll
    for (int n = 0; n < 16; ++n) A[n] = -__expf(A_log[d * 16 + n]);

    const float* dtp = delta_t + ((size_t)b * 1024 + d) * 1024 + lane * 16;
    const float* xp  = x + ((size_t)b * 1024 + lane * 16) * 1024 + d;
    const float* Bp  = Bg + (size_t)b * 16 * 1024 + lane * 16;
    const float* Cp  = Cg + (size_t)b * 16 * 1024 + lane * 16;
    float* yp = y + ((size_t)b * 1024 + lane * 16) * 1024 + d;

    float coff[16], soff[16], cum[16], S[16];

    // ---- pass 1: per-lane p-sums ----
    #pragma unroll
    for (int n = 0; n < 16; ++n) coff[n] = 0.f;
    #pragma unroll
    for (int w = 0; w < 4; ++w) {
        float4 d4 = ((const float4*)dtp)[w];
        #pragma unroll
        for (int n = 0; n < 16; ++n) {
            float a = A[n], s = coff[n];
            s += fminf(fmaxf(d4.x * a, -7.f), 20.f);
            s += fminf(fmaxf(d4.y * a, -7.f), 20.f);
            s += fminf(fmaxf(d4.z * a, -7.f), 20.f);
            s += fminf(fmaxf(d4.w * a, -7.f), 20.f);
            coff[n] = s;
        }
    }
    // exclusive scan across lanes
    #pragma unroll
    for (int n = 0; n < 16; ++n) {
        float v = coff[n];
        #pragma unroll
        for (int off = 1; off < 64; off <<= 1) {
            float t = __shfl_up(v, off);
            v += (lane >= off) ? t : 0.f;
        }
        float e = __shfl_up(v, 1);
        coff[n] = (lane > 0) ? e : 0.f;
    }

    // ---- pass 2: per-lane q-sums with stitched cum ----
    #pragma unroll
    for (int n = 0; n < 16; ++n) { cum[n] = coff[n]; soff[n] = 0.f; }
    #pragma unroll 1
    for (int w = 0; w < 4; ++w) {
        float4 d4 = ((const float4*)dtp)[w];
        const float* xpw = xp + (size_t)w * 4096;
        float u0 = d4.x * xpw[0];
        float u1 = d4.y * xpw[1024];
        float u2 = d4.z * xpw[2048];
        float u3 = d4.w * xpw[3072];
        #pragma unroll
        for (int n = 0; n < 16; ++n) {
            float4 b4 = *(const float4*)(Bp + (size_t)n * 1024 + w * 4);
            float a = A[n];
            float c = cum[n], q = soff[n];
            c += fminf(fmaxf(d4.x * a, -7.f), 20.f);
            q = fmaf(u0 * b4.x, __expf(fminf(-c, 20.f)), q);
            c += fminf(fmaxf(d4.y * a, -7.f), 20.f);
            q = fmaf(u1 * b4.y, __expf(fminf(-c, 20.f)), q);
            c += fminf(fmaxf(d4.z * a, -7.f), 20.f);
            q = fmaf(u2 * b4.z, __expf(fminf(-c, 20.f)), q);
            c += fminf(fmaxf(d4.w * a, -7.f), 20.f);
            q = fmaf(u3 * b4.w, __expf(fminf(-c, 20.f)), q);
            cum[n] = c; soff[n] = q;
        }
    }
    // exclusive scan across lanes
    #pragma unroll
    for (int n = 0; n < 16; ++n) {
        float v = soff[n];
        #pragma unroll
        for (int off = 1; off < 64; off <<= 1) {
            float t = __shfl_up(v, off);
            v += (lane >= off) ? t : 0.f;
        }
        float e = __shfl_up(v, 1);
        soff[n] = (lane > 0) ? e : 0.f;
    }

    // ---- pass 3: final walk, compute y ----
    #pragma unroll
    for (int n = 0; n < 16; ++n) { cum[n] = coff[n]; S[n] = soff[n]; }
    #pragma unroll 1
    for (int w = 0; w < 4; ++w) {
        float4 d4 = ((const float4*)dtp)[w];
        const float* xpw = xp + (size_t)w * 4096;
        float xv0 = xpw[0], xv1 = xpw[1024], xv2 = xpw[2048], xv3 = xpw[3072];
        float u0 = d4.x * xv0, u1 = d4.y * xv1, u2 = d4.z * xv2, u3 = d4.w * xv3;
        float y0 = xv0 * Dd, y1 = xv1 * Dd, y2 = xv2 * Dd, y3 = xv3 * Dd;
        #pragma unroll
        for (int n = 0; n < 16; ++n) {
            float4 b4 = *(const float4*)(Bp + (size_t)n * 1024 + w * 4);
            float4 c4 = *(const float4*)(Cp + (size_t)n * 1024 + w * 4);
            float a = A[n];
            float c = cum[n], s = S[n];

            c += fminf(fmaxf(d4.x * a, -7.f), 20.f);
            s = fmaf(u0 * b4.x, __expf(fminf(-c, 20.f)), s);
            y0 = fmaf(c4.x * __expf(fminf(c, 20.f)), s, y0);

            c += fminf(fmaxf(d4.y * a, -7.f), 20.f);
            s = fmaf(u1 * b4.y, __expf(fminf(-c, 20.f)), s);
            y1 = fmaf(c4.y * __expf(fminf(c, 20.f)), s, y1);

            c += fminf(fmaxf(d4.z * a, -7.f), 20.f);
            s = fmaf(u2 * b4.z, __expf(fminf(-c, 20.f)), s);
            y2 = fmaf(c4.z * __expf(fminf(c, 20.f)), s, y2);

            c += fminf(fmaxf(d4.w * a, -7.f), 20.f);
            s = fmaf(u3 * b4.w, __expf(fminf(-c, 20.f)), s);
            y3 = fmaf(c4.w * __expf(fminf(c, 20.f)), s, y3);

            cum[n] = c; S[n] = s;
        }
        float* ypw = yp + (size_t)w * 4096;
        ypw[0] = y0; ypw[1024] = y1; ypw[2048] = y2; ypw[3072] = y3;
    }
}

extern "C" void kernel_launch(void* const* d_in, const int* in_sizes, int n_in,
                              void* d_out, int out_size, void* d_ws, size_t ws_size,
                              hipStream_t stream) {
    const float* x    = (const float*)d_in[0];
    const float* Wx   = (const float*)d_in[1];
    const float* Wdt  = (const float*)d_in[2];
    const float* bdt  = (const float*)d_in[3];
    const float* Alog = (const float*)d_in[4];
    const float* Dvec = (const float*)d_in[5];
    float* y = (float*)d_out;

    // ws layout (floats): projdt 2048*64 | Bg 2*16*1024 | Cg 2*16*1024 | delta_t 2*1024*1024
    float* projdt  = (float*)d_ws;
    float* Bgp     = projdt + (size_t)2048 * 64;
    float* Cgp     = Bgp + (size_t)2 * 16 * 1024;
    float* delta_t = Cgp + (size_t)2 * 16 * 1024;

    proj_kernel<<<512, 384, 0, stream>>>(x, Wx, projdt, Bgp, Cgp);
    delta_kernel<<<512, 256, 0, stream>>>(projdt, Wdt, bdt, delta_t);
    scan_kernel<<<512, 256, 0, stream>>>(delta_t, x, Bgp, Cgp, Alog, Dvec, y);
}